// Round 7
// baseline (2397.359 us; speedup 1.0000x reference)
//
#include <hip/hip_runtime.h>
#include <hip/hip_bf16.h>
#include <climits>

#define NB 2
#define NPTS_ 16384
#define IMH 200
#define IMW 176
#define IMC 256
#define KTOT_ 2048
#define ROWS_ 4096
#define CIN_ 288
#define COUT_ 128

// ---------------------------------------------------------------- FPS core (templated slot count -> true VGPR arrays)
// 1024 threads: p = tid + (j << 10). Scan tracks max-dist only; index+coords
// extracted once per step via descending equality match (first-index tie-break).
template <int NL>
__device__ __forceinline__ void fps_core(
    int tid, int lane, int wv, int M, int K, int base,
    const float* __restrict__ pts,
    const unsigned short* __restrict__ s_idx,
    float4* __restrict__ s_k,
    float2 (* __restrict__ s_cdp)[16],
    float4 (* __restrict__ s_cxyz)[16]) {
#pragma clang fp contract(off)
  float lx[NL], ly[NL], lz[NL], ld[NL];
#pragma unroll
  for (int j = 0; j < NL; ++j) {
    int p = tid + (j << 10);
    bool v = p < M;
    int oi = v ? (int)s_idx[p] : 0;
    int gi = (base + oi) * 5;
    lx[j] = pts[gi + 1];
    ly[j] = pts[gi + 2];
    lz[j] = pts[gi + 3];
    ld[j] = v ? 1e10f : -1.0f;   // invalid slots pinned at -1: never selected
  }
  int gi0 = (base + (int)s_idx[0]) * 5;
  float lastx = pts[gi0 + 1], lasty = pts[gi0 + 2], lastz = pts[gi0 + 3];
  if (tid == 0) s_k[0] = make_float4(lastx, lasty, lastz, 0.f);

  int bufc = 0;
  for (int k = 1; k < K; ++k) {
    // scan: update running min-dist; track only the max (10 VALU/pt)
    float bd = -1.0f;
#pragma unroll
    for (int j = 0; j < NL; ++j) {
      float dx = lx[j] - lastx;
      float dy = ly[j] - lasty;
      float dz = lz[j] - lastz;
      float d = dx * dx;
      d += dy * dy;
      d += dz * dz;
      float nd = fminf(ld[j], d);
      ld[j] = nd;
      bd = fmaxf(bd, nd);
    }
    // once-per-step extract: smallest slot j achieving bd (descending -> first index)
    int bj = 0;
    float bx = lx[0], by = ly[0], bz = lz[0];
#pragma unroll
    for (int j = NL - 1; j >= 0; --j) {
      if (ld[j] == bd) { bj = j; bx = lx[j]; by = ly[j]; bz = lz[j]; }
    }
    int bp = tid + (bj << 10);
    // wave butterfly on (d, p); tie -> smallest compacted index p
    for (int o = 32; o > 0; o >>= 1) {
      float od = __shfl_xor(bd, o);
      int op = __shfl_xor(bp, o);
      if (od > bd || (od == bd && op < bp)) { bd = od; bp = op; }
    }
    // unique winner lane ((bp mod 1024) & 63) still holds its local coords
    if (lane == (bp & 63)) {
      s_cdp[bufc][wv] = make_float2(bd, __int_as_float(bp));
      s_cxyz[bufc][wv] = make_float4(bx, by, bz, 0.f);
    }
    __syncthreads();
    // all threads reduce the 16 wave candidates (broadcast LDS b64 reads)
    float2 c0 = s_cdp[bufc][0];
    float cd = c0.x; int cp = __float_as_int(c0.y); int cw = 0;
#pragma unroll
    for (int w = 1; w < 16; ++w) {
      float2 cc = s_cdp[bufc][w];
      float od = cc.x; int op = __float_as_int(cc.y);
      if (od > cd || (od == cd && op < cp)) { cd = od; cp = op; cw = w; }
    }
    float4 kk = s_cxyz[bufc][cw];
    lastx = kk.x; lasty = kk.y; lastz = kk.z;
    if (tid == 0) s_k[k] = kk;
    bufc ^= 1;
  }
}

// ---------------------------------------------------------------- FPS: 6 blocks = (batch, band), 1024 threads
__launch_bounds__(1024, 1)
__global__ void k_fps(const float* __restrict__ pts, const float* __restrict__ rngv,
                      float* __restrict__ out2) {
#pragma clang fp contract(off)
  const int blk = blockIdx.x;
  const int band = blk % 3, batch = blk / 3;
  const int K = (band == 0) ? 1024 : 512;
  const int off = (band == 0) ? 0 : (band == 1 ? 1024 : 1536);
  const int base = batch * NPTS_;

  __shared__ unsigned short s_idx[NPTS_];   // 32 KB compacted -> original idx
  __shared__ float4 s_k[1024];              // 16 KB selected keypoints
  __shared__ float2 s_cdp[2][16];
  __shared__ float4 s_cxyz[2][16];
  __shared__ int s_wsum[16];

  const int tid = threadIdx.x, lane = tid & 63, wv = tid >> 6;

  // ---- mask own contiguous 16-point chunk (order-preserving compaction)
  unsigned int vm = 0u;
  for (int j = 0; j < 16; ++j) {
    float r = rngv[base + tid * 16 + j];
    bool sm = (r > 0.0f) && (r < 25.0f);
    bool lm = (r > 45.0f);
    bool v = (band == 0) ? sm : (band == 2 ? lm : (!lm && !sm));
    vm |= (v ? 1u : 0u) << j;
  }
  int cnt = __popc(vm);
  int inc = cnt;
  for (int d = 1; d < 64; d <<= 1) {
    int o = __shfl_up(inc, d);
    if (lane >= d) inc += o;
  }
  if (lane == 63) s_wsum[wv] = inc;
  __syncthreads();
  int woff = 0, M = 0;
  for (int w = 0; w < 16; ++w) {
    if (w < wv) woff += s_wsum[w];
    M += s_wsum[w];
  }
  int myoff = woff + inc - cnt;
  unsigned int t = vm;
  while (t) {
    int b = __builtin_ctz(t);
    t &= t - 1;
    s_idx[myoff++] = (unsigned short)(tid * 16 + b);
  }
  __syncthreads();

  // ---- dispatch to size-specialized serial loop (arrays in VGPRs)
  int nl = (M + 1023) >> 10;
  if (nl <= 4)       fps_core<4> (tid, lane, wv, M, K, base, pts, s_idx, s_k, s_cdp, s_cxyz);
  else if (nl <= 6)  fps_core<6> (tid, lane, wv, M, K, base, pts, s_idx, s_k, s_cdp, s_cxyz);
  else if (nl <= 8)  fps_core<8> (tid, lane, wv, M, K, base, pts, s_idx, s_k, s_cdp, s_cxyz);
  else if (nl <= 12) fps_core<12>(tid, lane, wv, M, K, base, pts, s_idx, s_k, s_cdp, s_cxyz);
  else               fps_core<16>(tid, lane, wv, M, K, base, pts, s_idx, s_k, s_cdp, s_cxyz);

  // ---- epilogue: stream keypoints to out2
  __syncthreads();
  const float batf = (float)batch;
  for (int i = tid; i < K; i += 1024) {
    int g = (batch * KTOT_ + off + i) * 4;
    float4 kk = s_k[i];
    out2[g + 0] = batf;
    out2[g + 1] = kk.x;
    out2[g + 2] = kk.y;
    out2[g + 3] = kk.z;
  }
}

// ---------------------------------------------------------------- bilinear BEV gather, native [B,C,H,W]
__launch_bounds__(256)
__global__ void k_bev(const float* __restrict__ sf, const float* __restrict__ out2,
                      float* __restrict__ out1) {
#pragma clang fp contract(off)
  int tid = threadIdx.x, lane = tid & 63, wv = tid >> 6;
  int g = blockIdx.x * 4 + wv;
  if (g >= ROWS_) return;
  int b = g >> 11;
  float xx = out2[g * 4 + 1], yy = out2[g * 4 + 2];
  float x = (xx - 0.0f) / 0.05f / 8.0f;
  float y = (yy - (-40.0f)) / 0.05f / 8.0f;
  int x0 = (int)floorf(x), y0 = (int)floorf(y);
  int x1 = x0 + 1, y1 = y0 + 1;
  x0 = min(max(x0, 0), IMW - 1); x1 = min(max(x1, 0), IMW - 1);
  y0 = min(max(y0, 0), IMH - 1); y1 = min(max(y1, 0), IMH - 1);
  float x0f = (float)x0, x1f = (float)x1, y0f = (float)y0, y1f = (float)y1;
  float wa = (x1f - x) * (y1f - y);
  float wb = (x1f - x) * (y - y0f);
  float wc = (x - x0f) * (y1f - y);
  float wd = (x - x0f) * (y - y0f);
  int oa = y0 * IMW + x0;
  int ob = y1 * IMW + x0;
  int oc = y0 * IMW + x1;
  int od = y1 * IMW + x1;
  const float* pb = sf + (size_t)b * IMC * IMH * IMW;
  for (int j = 0; j < 4; ++j) {
    int c = lane * 4 + j;
    const float* pc = pb + (size_t)c * (IMH * IMW);
    float o = pc[oa] * wa;
    o += pc[ob] * wb;
    o += pc[oc] * wc;
    o += pc[od] * wd;
    out1[(size_t)g * CIN_ + c] = o;
  }
}

// ---------------------------------------------------------------- SA: ball query + MLP + maxpool (wave per kp)
__launch_bounds__(256)
__global__ void k_sa(const float* __restrict__ pts, const float* __restrict__ out2,
                     const float* __restrict__ w0, const float* __restrict__ bn0,
                     const float* __restrict__ w1, const float* __restrict__ bn1,
                     float* __restrict__ out1) {
#pragma clang fp contract(off)
  __shared__ float s_w0[128];   // [2][4][16]
  __shared__ float s_w1[512];   // [2][16][16]
  __shared__ float s_s0[32], s_m0[32], s_b0[32];  // [2][16]
  __shared__ float s_s1[32], s_m1[32], s_b1[32];
  int tid = threadIdx.x;
  for (int i = tid; i < 128; i += 256) s_w0[i] = w0[i];
  for (int i = tid; i < 512; i += 256) s_w1[i] = w1[i];
  if (tid < 32) {
    int rad = tid >> 4, c = tid & 15;
    int bb = rad * 64;
    {
      float gg = bn0[bb + c], bbt = bn0[bb + 16 + c];
      float mm = bn0[bb + 32 + c], vv = bn0[bb + 48 + c];
      s_s0[tid] = gg / sqrtf(vv + 1e-5f); s_m0[tid] = mm; s_b0[tid] = bbt;
    }
    {
      float gg = bn1[bb + c], bbt = bn1[bb + 16 + c];
      float mm = bn1[bb + 32 + c], vv = bn1[bb + 48 + c];
      s_s1[tid] = gg / sqrtf(vv + 1e-5f); s_m1[tid] = mm; s_b1[tid] = bbt;
    }
  }
  __syncthreads();

  int lane = tid & 63, wv = tid >> 6;
  int g = blockIdx.x * 4 + wv;
  if (g >= ROWS_) return;
  int batch = g >> 11;
  int base = batch * NPTS_;
  float kx = out2[g * 4 + 1];
  float ky = out2[g * 4 + 2];
  float kz = out2[g * 4 + 3];

  int myrad = (lane >> 4) & 1, myslot = lane & 15;
  int c1 = 0, c2 = 0, first1 = -1, first2 = -1, myidx = -1;
  for (int r = 0; r < NPTS_ / 64; ++r) {
    int gi = (base + r * 64 + lane) * 5;
    float dx = kx - pts[gi + 1];
    float dy = ky - pts[gi + 2];
    float dz = kz - pts[gi + 3];
    float d = dx * dx;
    d += dy * dy;
    d += dz * dz;
    unsigned long long m1 = __ballot(d < 1.0f);
    unsigned long long m2 = __ballot(d < 4.0f);
    while (m1 && c1 < 16) {
      int bpos = __builtin_ctzll(m1); m1 &= m1 - 1;
      int pi = r * 64 + bpos;
      if (c1 == 0) first1 = pi;
      if (lane < 32 && myrad == 0 && c1 == myslot) myidx = pi;
      ++c1;
    }
    while (m2 && c2 < 16) {
      int bpos = __builtin_ctzll(m2); m2 &= m2 - 1;
      int pi = r * 64 + bpos;
      if (c2 == 0) first2 = pi;
      if (lane < 32 && myrad == 1 && c2 == myslot) myidx = pi;
      ++c2;
    }
    if (c1 >= 16 && c2 >= 16) break;
  }
  int fi = (myrad == 0) ? first1 : first2;
  bool use = (lane < 32) && (fi >= 0);
  if (myidx < 0) myidx = (fi >= 0) ? fi : 0;
  float gx = 0.f, gy = 0.f, gz = 0.f, gf = 0.f;
  if (use) {
    int gi = (base + myidx) * 5;
    gx = pts[gi + 1] - kx;
    gy = pts[gi + 2] - ky;
    gz = pts[gi + 3] - kz;
    gf = pts[gi + 4];
  }
  const float* W0 = s_w0 + myrad * 64;    // [4][16]
  const float* W1 = s_w1 + myrad * 256;   // [16][16]
  int bc = myrad * 16;
  float h1[16];
  for (int c = 0; c < 16; ++c) {
    float a = gx * W0[c];
    a += gy * W0[16 + c];
    a += gz * W0[32 + c];
    a += gf * W0[48 + c];
    h1[c] = fmaxf((a - s_m0[bc + c]) * s_s0[bc + c] + s_b0[bc + c], 0.f);
  }
  for (int c = 0; c < 16; ++c) {
    float a = 0.f;
    for (int k = 0; k < 16; ++k) a += h1[k] * W1[k * 16 + c];
    float h2 = fmaxf((a - s_m1[bc + c]) * s_s1[bc + c] + s_b1[bc + c], 0.f);
    h2 = fmaxf(h2, __shfl_xor(h2, 1));
    h2 = fmaxf(h2, __shfl_xor(h2, 2));
    h2 = fmaxf(h2, __shfl_xor(h2, 4));
    h2 = fmaxf(h2, __shfl_xor(h2, 8));
    if (lane < 32 && myslot == 0) {
      int col = 256 + myrad * 16 + c;
      out1[(size_t)g * CIN_ + col] = h2;
    }
  }
}

// ---------------------------------------------------------------- fusion: [4096,288]@[288,128] + BN + ReLU
__launch_bounds__(128)
__global__ void k_fuse(const float* __restrict__ out1, const float* __restrict__ fw,
                       const float* __restrict__ fbn, float* __restrict__ out0) {
  int r = blockIdx.x, c = threadIdx.x;
  __shared__ float sA[CIN_];
  for (int i = c; i < CIN_; i += 128) sA[i] = out1[(size_t)r * CIN_ + i];
  __syncthreads();
  float acc = 0.f;
  for (int k = 0; k < CIN_; ++k) acc += sA[k] * fw[k * COUT_ + c];
  float gg = fbn[c], bb = fbn[COUT_ + c];
  float mm = fbn[2 * COUT_ + c], vv = fbn[3 * COUT_ + c];
  float sc = gg / sqrtf(vv + 1e-5f);
  float o = fmaxf((acc - mm) * sc + bb, 0.f);
  out0[(size_t)r * COUT_ + c] = o;
}

// ---------------------------------------------------------------- launch (ZERO d_ws usage)
extern "C" void kernel_launch(void* const* d_in, const int* in_sizes, int n_in,
                              void* d_out, int out_size, void* d_ws, size_t ws_size,
                              hipStream_t stream) {
  const float* points = (const float*)d_in[0];
  const float* rng    = (const float*)d_in[1];
  const float* sf     = (const float*)d_in[2];
  const float* w0     = (const float*)d_in[3];
  const float* bn0    = (const float*)d_in[4];
  const float* w1     = (const float*)d_in[5];
  const float* bn1    = (const float*)d_in[6];
  const float* fw     = (const float*)d_in[7];
  const float* fbn    = (const float*)d_in[8];

  float* out0 = (float*)d_out;                         // fused [4096,128]
  float* out1 = out0 + (size_t)ROWS_ * COUT_;          // feats [4096,288]
  float* out2 = out1 + (size_t)ROWS_ * CIN_;           // point_coords [4096,4]

  k_fps<<<6, 1024, 0, stream>>>(points, rng, out2);
  k_bev<<<ROWS_ / 4, 256, 0, stream>>>(sf, out2, out1);
  k_sa<<<ROWS_ / 4, 256, 0, stream>>>(points, out2, w0, bn0, w1, bn1, out1);
  k_fuse<<<ROWS_, 128, 0, stream>>>(out1, fw, fbn, out0);
}

// Round 8
// 1496.571 us; speedup vs baseline: 1.6019x; 1.6019x over previous
//
#include <hip/hip_runtime.h>
#include <hip/hip_bf16.h>
#include <climits>

#define NB 2
#define NPTS_ 16384
#define IMH 200
#define IMW 176
#define IMC 256
#define KTOT_ 2048
#define ROWS_ 4096
#define CIN_ 288
#define COUT_ 128

typedef unsigned long long u64;
typedef unsigned int u32;

// ---------------------------------------------------------------- FPS core
// 1024 threads, slot p = tid + (j<<10). Scan tracks max-dist only; slot/coords
// recovered once per step by descending equality match (first-index tie-break).
// Candidate key packs (dist_bits<<32)|~p: u64 max == (max d, tie -> min p).
template <int NL>
__device__ __forceinline__ void fps_core(
    int tid, int lane, int wv, int M, int K, int base,
    const float* __restrict__ pts,
    const unsigned short* __restrict__ s_idx,
    float4* __restrict__ s_k,
    u64 (* __restrict__ s_key)[16],
    float4 (* __restrict__ s_cxyz)[16]) {
#pragma clang fp contract(off)
  float lx[NL], ly[NL], lz[NL], ld[NL];
#pragma unroll
  for (int j = 0; j < NL; ++j) {
    int p = tid + (j << 10);
    bool v = p < M;
    int oi = v ? (int)s_idx[p] : 0;
    int gi = (base + oi) * 5;
    lx[j] = pts[gi + 1];
    ly[j] = pts[gi + 2];
    lz[j] = pts[gi + 3];
    ld[j] = v ? 1e10f : -1.0f;   // invalid slots pinned at -1: never selected
  }
  int gi0 = (base + (int)s_idx[0]) * 5;
  float lastx = pts[gi0 + 1], lasty = pts[gi0 + 2], lastz = pts[gi0 + 3];
  if (tid == 0) s_k[0] = make_float4(lastx, lasty, lastz, 0.f);

  int bufc = 0;
  for (int k = 1; k < K; ++k) {
    // scan: update running min-dist; track only the max (slot 0 always valid -> bd >= 0)
    float bd = -1.0f;
#pragma unroll
    for (int j = 0; j < NL; ++j) {
      float dx = lx[j] - lastx;
      float dy = ly[j] - lasty;
      float dz = lz[j] - lastz;
      float d = dx * dx;
      d += dy * dy;
      d += dz * dz;
      float nd = fminf(ld[j], d);
      ld[j] = nd;
      bd = fmaxf(bd, nd);
    }
    // extract smallest slot j achieving bd (descending -> first index); bd>=0 never matches -1
    int bj = 0;
    float bx = lx[0], by = ly[0], bz = lz[0];
#pragma unroll
    for (int j = NL - 1; j >= 0; --j) {
      if (ld[j] == bd) { bj = j; bx = lx[j]; by = ly[j]; bz = lz[j]; }
    }
    int bp = tid + (bj << 10);
    u64 key = ((u64)__float_as_uint(bd) << 32) | (u32)(~bp);
    // wave butterfly: u64 max
    for (int o = 32; o > 0; o >>= 1) {
      u64 ok = __shfl_xor(key, o);
      key = (ok > key) ? ok : key;
    }
    // unique winner lane still holds its local coords
    u32 wp = ~(u32)key;
    if (lane == (int)(wp & 63)) {
      s_key[bufc][wv] = key;
      s_cxyz[bufc][wv] = make_float4(bx, by, bz, 0.f);
    }
    __syncthreads();
    // cross-wave: tree-reduce the 16 wave keys (broadcast LDS b64 reads)
    u64 a0 = s_key[bufc][0],  a1 = s_key[bufc][1],  a2 = s_key[bufc][2],  a3 = s_key[bufc][3];
    u64 a4 = s_key[bufc][4],  a5 = s_key[bufc][5],  a6 = s_key[bufc][6],  a7 = s_key[bufc][7];
    u64 a8 = s_key[bufc][8],  a9 = s_key[bufc][9],  aa = s_key[bufc][10], ab = s_key[bufc][11];
    u64 ac = s_key[bufc][12], ad = s_key[bufc][13], ae = s_key[bufc][14], af = s_key[bufc][15];
    u64 b0 = (a1 > a0) ? a1 : a0;
    u64 b1 = (a3 > a2) ? a3 : a2;
    u64 b2 = (a5 > a4) ? a5 : a4;
    u64 b3 = (a7 > a6) ? a7 : a6;
    u64 b4 = (a9 > a8) ? a9 : a8;
    u64 b5 = (ab > aa) ? ab : aa;
    u64 b6 = (ad > ac) ? ad : ac;
    u64 b7 = (af > ae) ? af : ae;
    u64 c0 = (b1 > b0) ? b1 : b0;
    u64 c1 = (b3 > b2) ? b3 : b2;
    u64 c2 = (b5 > b4) ? b5 : b4;
    u64 c3 = (b7 > b6) ? b7 : b6;
    u64 d0 = (c1 > c0) ? c1 : c0;
    u64 d1 = (c3 > c2) ? c3 : c2;
    u64 kk_key = (d1 > d0) ? d1 : d0;
    int cw = (int)((~(u32)kk_key & 1023u) >> 6);   // winner tid -> wave
    float4 kk = s_cxyz[bufc][cw];
    lastx = kk.x; lasty = kk.y; lastz = kk.z;
    if (tid == 0) s_k[k] = kk;
    bufc ^= 1;
  }
}

// ---------------------------------------------------------------- FPS: grid 12 = (class, batch, band), 1024 threads
__launch_bounds__(1024, 4)
__global__ void k_fps(const float* __restrict__ pts, const float* __restrict__ rngv,
                      float* __restrict__ out2) {
#pragma clang fp contract(off)
  const int blk = blockIdx.x;
  const int cls = blk / 6;                // 0: NL=4 (M<=4096), 1: NL=8 (M<=8192)
  const int sub = blk % 6;
  const int band = sub % 3, batch = sub / 3;
  const int K = (band == 0) ? 1024 : 512;
  const int off = (band == 0) ? 0 : (band == 1 ? 1024 : 1536);
  const int base = batch * NPTS_;

  __shared__ unsigned short s_idx[8192];    // 16 KB compacted -> original idx
  __shared__ float4 s_k[1024];              // 16 KB selected keypoints
  __shared__ u64 s_key[2][16];
  __shared__ float4 s_cxyz[2][16];
  __shared__ int s_wsum[16];

  const int tid = threadIdx.x, lane = tid & 63, wv = tid >> 6;

  // ---- mask own contiguous 16-point chunk (order-preserving compaction)
  unsigned int vm = 0u;
  for (int j = 0; j < 16; ++j) {
    float r = rngv[base + tid * 16 + j];
    bool sm = (r > 0.0f) && (r < 25.0f);
    bool lm = (r > 45.0f);
    bool v = (band == 0) ? sm : (band == 2 ? lm : (!lm && !sm));
    vm |= (v ? 1u : 0u) << j;
  }
  int cnt = __popc(vm);
  int inc = cnt;
  for (int d = 1; d < 64; d <<= 1) {
    int o = __shfl_up(inc, d);
    if (lane >= d) inc += o;
  }
  if (lane == 63) s_wsum[wv] = inc;
  __syncthreads();
  int woff = 0, M = 0;
  for (int w = 0; w < 16; ++w) {
    if (w < wv) woff += s_wsum[w];
    M += s_wsum[w];
  }
  // class check: exactly one class kernel-instance handles this band
  int myclass = (M <= 4096) ? 0 : 1;
  if (myclass != cls) return;

  int myoff = woff + inc - cnt;
  unsigned int t = vm;
  while (t) {
    int b = __builtin_ctz(t);
    t &= t - 1;
    if (myoff < 8192) s_idx[myoff] = (unsigned short)(tid * 16 + b);
    ++myoff;
  }
  __syncthreads();

  if (cls == 0) fps_core<4>(tid, lane, wv, M, K, base, pts, s_idx, s_k, s_key, s_cxyz);
  else          fps_core<8>(tid, lane, wv, M, K, base, pts, s_idx, s_k, s_key, s_cxyz);

  // ---- epilogue: stream keypoints to out2
  __syncthreads();
  const float batf = (float)batch;
  for (int i = tid; i < K; i += 1024) {
    int g = (batch * KTOT_ + off + i) * 4;
    float4 kk = s_k[i];
    out2[g + 0] = batf;
    out2[g + 1] = kk.x;
    out2[g + 2] = kk.y;
    out2[g + 3] = kk.z;
  }
}

// ---------------------------------------------------------------- bilinear BEV gather, native [B,C,H,W]
__launch_bounds__(256)
__global__ void k_bev(const float* __restrict__ sf, const float* __restrict__ out2,
                      float* __restrict__ out1) {
#pragma clang fp contract(off)
  int tid = threadIdx.x, lane = tid & 63, wv = tid >> 6;
  int g = blockIdx.x * 4 + wv;
  if (g >= ROWS_) return;
  int b = g >> 11;
  float xx = out2[g * 4 + 1], yy = out2[g * 4 + 2];
  float x = (xx - 0.0f) / 0.05f / 8.0f;
  float y = (yy - (-40.0f)) / 0.05f / 8.0f;
  int x0 = (int)floorf(x), y0 = (int)floorf(y);
  int x1 = x0 + 1, y1 = y0 + 1;
  x0 = min(max(x0, 0), IMW - 1); x1 = min(max(x1, 0), IMW - 1);
  y0 = min(max(y0, 0), IMH - 1); y1 = min(max(y1, 0), IMH - 1);
  float x0f = (float)x0, x1f = (float)x1, y0f = (float)y0, y1f = (float)y1;
  float wa = (x1f - x) * (y1f - y);
  float wb = (x1f - x) * (y - y0f);
  float wc = (x - x0f) * (y1f - y);
  float wd = (x - x0f) * (y - y0f);
  int oa = y0 * IMW + x0;
  int ob = y1 * IMW + x0;
  int oc = y0 * IMW + x1;
  int od = y1 * IMW + x1;
  const float* pb = sf + (size_t)b * IMC * IMH * IMW;
  for (int j = 0; j < 4; ++j) {
    int c = lane * 4 + j;
    const float* pc = pb + (size_t)c * (IMH * IMW);
    float o = pc[oa] * wa;
    o += pc[ob] * wb;
    o += pc[oc] * wc;
    o += pc[od] * wd;
    out1[(size_t)g * CIN_ + c] = o;
  }
}

// ---------------------------------------------------------------- SA: ball query + MLP + maxpool (wave per kp)
__launch_bounds__(256)
__global__ void k_sa(const float* __restrict__ pts, const float* __restrict__ out2,
                     const float* __restrict__ w0, const float* __restrict__ bn0,
                     const float* __restrict__ w1, const float* __restrict__ bn1,
                     float* __restrict__ out1) {
#pragma clang fp contract(off)
  __shared__ float s_w0[128];   // [2][4][16]
  __shared__ float s_w1[512];   // [2][16][16]
  __shared__ float s_s0[32], s_m0[32], s_b0[32];  // [2][16]
  __shared__ float s_s1[32], s_m1[32], s_b1[32];
  int tid = threadIdx.x;
  for (int i = tid; i < 128; i += 256) s_w0[i] = w0[i];
  for (int i = tid; i < 512; i += 256) s_w1[i] = w1[i];
  if (tid < 32) {
    int rad = tid >> 4, c = tid & 15;
    int bb = rad * 64;
    {
      float gg = bn0[bb + c], bbt = bn0[bb + 16 + c];
      float mm = bn0[bb + 32 + c], vv = bn0[bb + 48 + c];
      s_s0[tid] = gg / sqrtf(vv + 1e-5f); s_m0[tid] = mm; s_b0[tid] = bbt;
    }
    {
      float gg = bn1[bb + c], bbt = bn1[bb + 16 + c];
      float mm = bn1[bb + 32 + c], vv = bn1[bb + 48 + c];
      s_s1[tid] = gg / sqrtf(vv + 1e-5f); s_m1[tid] = mm; s_b1[tid] = bbt;
    }
  }
  __syncthreads();

  int lane = tid & 63, wv = tid >> 6;
  int g = blockIdx.x * 4 + wv;
  if (g >= ROWS_) return;
  int batch = g >> 11;
  int base = batch * NPTS_;
  float kx = out2[g * 4 + 1];
  float ky = out2[g * 4 + 2];
  float kz = out2[g * 4 + 3];

  int myrad = (lane >> 4) & 1, myslot = lane & 15;
  int c1 = 0, c2 = 0, first1 = -1, first2 = -1, myidx = -1;
  for (int r = 0; r < NPTS_ / 64; ++r) {
    int gi = (base + r * 64 + lane) * 5;
    float dx = kx - pts[gi + 1];
    float dy = ky - pts[gi + 2];
    float dz = kz - pts[gi + 3];
    float d = dx * dx;
    d += dy * dy;
    d += dz * dz;
    unsigned long long m1 = __ballot(d < 1.0f);
    unsigned long long m2 = __ballot(d < 4.0f);
    while (m1 && c1 < 16) {
      int bpos = __builtin_ctzll(m1); m1 &= m1 - 1;
      int pi = r * 64 + bpos;
      if (c1 == 0) first1 = pi;
      if (lane < 32 && myrad == 0 && c1 == myslot) myidx = pi;
      ++c1;
    }
    while (m2 && c2 < 16) {
      int bpos = __builtin_ctzll(m2); m2 &= m2 - 1;
      int pi = r * 64 + bpos;
      if (c2 == 0) first2 = pi;
      if (lane < 32 && myrad == 1 && c2 == myslot) myidx = pi;
      ++c2;
    }
    if (c1 >= 16 && c2 >= 16) break;
  }
  int fi = (myrad == 0) ? first1 : first2;
  bool use = (lane < 32) && (fi >= 0);
  if (myidx < 0) myidx = (fi >= 0) ? fi : 0;
  float gx = 0.f, gy = 0.f, gz = 0.f, gf = 0.f;
  if (use) {
    int gi = (base + myidx) * 5;
    gx = pts[gi + 1] - kx;
    gy = pts[gi + 2] - ky;
    gz = pts[gi + 3] - kz;
    gf = pts[gi + 4];
  }
  const float* W0 = s_w0 + myrad * 64;    // [4][16]
  const float* W1 = s_w1 + myrad * 256;   // [16][16]
  int bc = myrad * 16;
  float h1[16];
  for (int c = 0; c < 16; ++c) {
    float a = gx * W0[c];
    a += gy * W0[16 + c];
    a += gz * W0[32 + c];
    a += gf * W0[48 + c];
    h1[c] = fmaxf((a - s_m0[bc + c]) * s_s0[bc + c] + s_b0[bc + c], 0.f);
  }
  for (int c = 0; c < 16; ++c) {
    float a = 0.f;
    for (int k = 0; k < 16; ++k) a += h1[k] * W1[k * 16 + c];
    float h2 = fmaxf((a - s_m1[bc + c]) * s_s1[bc + c] + s_b1[bc + c], 0.f);
    h2 = fmaxf(h2, __shfl_xor(h2, 1));
    h2 = fmaxf(h2, __shfl_xor(h2, 2));
    h2 = fmaxf(h2, __shfl_xor(h2, 4));
    h2 = fmaxf(h2, __shfl_xor(h2, 8));
    if (lane < 32 && myslot == 0) {
      int col = 256 + myrad * 16 + c;
      out1[(size_t)g * CIN_ + col] = h2;
    }
  }
}

// ---------------------------------------------------------------- fusion: [4096,288]@[288,128] + BN + ReLU
__launch_bounds__(128)
__global__ void k_fuse(const float* __restrict__ out1, const float* __restrict__ fw,
                       const float* __restrict__ fbn, float* __restrict__ out0) {
  int r = blockIdx.x, c = threadIdx.x;
  __shared__ float sA[CIN_];
  for (int i = c; i < CIN_; i += 128) sA[i] = out1[(size_t)r * CIN_ + i];
  __syncthreads();
  float acc = 0.f;
  for (int k = 0; k < CIN_; ++k) acc += sA[k] * fw[k * COUT_ + c];
  float gg = fbn[c], bb = fbn[COUT_ + c];
  float mm = fbn[2 * COUT_ + c], vv = fbn[3 * COUT_ + c];
  float sc = gg / sqrtf(vv + 1e-5f);
  float o = fmaxf((acc - mm) * sc + bb, 0.f);
  out0[(size_t)r * COUT_ + c] = o;
}

// ---------------------------------------------------------------- launch (ZERO d_ws usage)
extern "C" void kernel_launch(void* const* d_in, const int* in_sizes, int n_in,
                              void* d_out, int out_size, void* d_ws, size_t ws_size,
                              hipStream_t stream) {
  const float* points = (const float*)d_in[0];
  const float* rng    = (const float*)d_in[1];
  const float* sf     = (const float*)d_in[2];
  const float* w0     = (const float*)d_in[3];
  const float* bn0    = (const float*)d_in[4];
  const float* w1     = (const float*)d_in[5];
  const float* bn1    = (const float*)d_in[6];
  const float* fw     = (const float*)d_in[7];
  const float* fbn    = (const float*)d_in[8];

  float* out0 = (float*)d_out;                         // fused [4096,128]
  float* out1 = out0 + (size_t)ROWS_ * COUT_;          // feats [4096,288]
  float* out2 = out1 + (size_t)ROWS_ * CIN_;           // point_coords [4096,4]

  k_fps<<<12, 1024, 0, stream>>>(points, rng, out2);
  k_bev<<<ROWS_ / 4, 256, 0, stream>>>(sf, out2, out1);
  k_sa<<<ROWS_ / 4, 256, 0, stream>>>(points, out2, w0, bn0, w1, bn1, out1);
  k_fuse<<<ROWS_, 128, 0, stream>>>(out1, fw, fbn, out0);
}

// Round 9
// 1314.177 us; speedup vs baseline: 1.8242x; 1.1388x over previous
//
#include <hip/hip_runtime.h>
#include <hip/hip_bf16.h>
#include <climits>

#define NB 2
#define NPTS_ 16384
#define IMH 200
#define IMW 176
#define IMC 256
#define KTOT_ 2048
#define ROWS_ 4096
#define CIN_ 288
#define COUT_ 128

typedef unsigned long long u64;
typedef unsigned int u32;

// DPP wave64 reduction stages (VALU-only; result lands in lane 63).
// update_dpp(old=v, src=v): lanes with invalid source keep old -> op(v,v)=v, harmless.
#define DPP_MAXF(v, ctrl)                                                              \
  do {                                                                                 \
    int _s = __builtin_amdgcn_update_dpp(__float_as_int(v), __float_as_int(v), (ctrl), \
                                         0xF, 0xF, false);                             \
    (v) = fmaxf((v), __int_as_float(_s));                                              \
  } while (0)
#define DPP_MINU(v, ctrl)                                                              \
  do {                                                                                 \
    int _s = __builtin_amdgcn_update_dpp((int)(v), (int)(v), (ctrl), 0xF, 0xF, false); \
    (v) = ((u32)_s < (v)) ? (u32)_s : (v);                                             \
  } while (0)

// ---------------------------------------------------------------- FPS core
// 1024 threads, slot p = tid + (j<<10). Scan tracks max-dist only; slot/coords
// recovered once per step by descending equality match (first-index tie-break).
// Wave reduce: DPP max-d (6 stages) + DPP min-p among d-ties (6 stages), all VALU.
template <int NL>
__device__ __forceinline__ void fps_core(
    int tid, int lane, int wv, int M, int K, int base,
    const float* __restrict__ pts,
    const unsigned short* __restrict__ s_idx,
    float4* __restrict__ s_k,
    u64 (* __restrict__ s_key)[16],
    float4 (* __restrict__ s_cxyz)[16]) {
#pragma clang fp contract(off)
  float lx[NL], ly[NL], lz[NL], ld[NL];
#pragma unroll
  for (int j = 0; j < NL; ++j) {
    int p = tid + (j << 10);
    bool v = p < M;
    int oi = v ? (int)s_idx[p] : 0;
    int gi = (base + oi) * 5;
    lx[j] = pts[gi + 1];
    ly[j] = pts[gi + 2];
    lz[j] = pts[gi + 3];
    ld[j] = v ? 1e10f : -1.0f;   // invalid slots pinned at -1: never selected (bd >= 0 always)
  }
  int gi0 = (base + (int)s_idx[0]) * 5;
  float lastx = pts[gi0 + 1], lasty = pts[gi0 + 2], lastz = pts[gi0 + 3];
  if (tid == 0) s_k[0] = make_float4(lastx, lasty, lastz, 0.f);

  int bufc = 0;
  for (int k = 1; k < K; ++k) {
    // scan: update running min-dist; track only the max (slot 0 always valid since M > 1024)
    float bd = -1.0f;
#pragma unroll
    for (int j = 0; j < NL; ++j) {
      float dx = lx[j] - lastx;
      float dy = ly[j] - lasty;
      float dz = lz[j] - lastz;
      float d = dx * dx;
      d += dy * dy;
      d += dz * dz;
      float nd = fminf(ld[j], d);
      ld[j] = nd;
      bd = fmaxf(bd, nd);
    }
    // extract smallest slot j achieving bd (descending -> first index); bd>=0 never matches -1
    int bj = 0;
    float bx = lx[0], by = ly[0], bz = lz[0];
#pragma unroll
    for (int j = NL - 1; j >= 0; --j) {
      if (ld[j] == bd) { bj = j; bx = lx[j]; by = ly[j]; bz = lz[j]; }
    }
    int bp = tid + (bj << 10);

    // wave max-d via DPP (VALU only), broadcast from lane 63
    float rd = bd;
    DPP_MAXF(rd, 0x111);  // row_shr:1
    DPP_MAXF(rd, 0x112);  // row_shr:2
    DPP_MAXF(rd, 0x114);  // row_shr:4
    DPP_MAXF(rd, 0x118);  // row_shr:8
    DPP_MAXF(rd, 0x142);  // row_bcast:15
    DPP_MAXF(rd, 0x143);  // row_bcast:31
    float maxd = __int_as_float(__builtin_amdgcn_readlane(__float_as_int(rd), 63));

    // wave min-p among lanes holding maxd (p unique per lane -> unique winner)
    u32 pc = (bd == maxd) ? (u32)bp : 0xFFFFFFFFu;
    u32 rp = pc;
    DPP_MINU(rp, 0x111);
    DPP_MINU(rp, 0x112);
    DPP_MINU(rp, 0x114);
    DPP_MINU(rp, 0x118);
    DPP_MINU(rp, 0x142);
    DPP_MINU(rp, 0x143);
    u32 wp = (u32)__builtin_amdgcn_readlane((int)rp, 63);

    if (pc == wp) {   // the unique wave-winner lane still holds its local coords
      s_key[bufc][wv] = ((u64)__float_as_uint(maxd) << 32) | (u32)(~wp);
      s_cxyz[bufc][wv] = make_float4(bx, by, bz, 0.f);
    }
    __syncthreads();
    // cross-wave: tree-reduce the 16 wave keys (broadcast LDS b64 reads)
    u64 a0 = s_key[bufc][0],  a1 = s_key[bufc][1],  a2 = s_key[bufc][2],  a3 = s_key[bufc][3];
    u64 a4 = s_key[bufc][4],  a5 = s_key[bufc][5],  a6 = s_key[bufc][6],  a7 = s_key[bufc][7];
    u64 a8 = s_key[bufc][8],  a9 = s_key[bufc][9],  aa = s_key[bufc][10], ab = s_key[bufc][11];
    u64 ac = s_key[bufc][12], ad = s_key[bufc][13], ae = s_key[bufc][14], af = s_key[bufc][15];
    u64 b0 = (a1 > a0) ? a1 : a0;
    u64 b1 = (a3 > a2) ? a3 : a2;
    u64 b2 = (a5 > a4) ? a5 : a4;
    u64 b3 = (a7 > a6) ? a7 : a6;
    u64 b4 = (a9 > a8) ? a9 : a8;
    u64 b5 = (ab > aa) ? ab : aa;
    u64 b6 = (ad > ac) ? ad : ac;
    u64 b7 = (af > ae) ? af : ae;
    u64 c0 = (b1 > b0) ? b1 : b0;
    u64 c1 = (b3 > b2) ? b3 : b2;
    u64 c2 = (b5 > b4) ? b5 : b4;
    u64 c3 = (b7 > b6) ? b7 : b6;
    u64 d0 = (c1 > c0) ? c1 : c0;
    u64 d1 = (c3 > c2) ? c3 : c2;
    u64 kk_key = (d1 > d0) ? d1 : d0;
    int cw = (int)((~(u32)kk_key & 1023u) >> 6);   // winner tid -> wave
    float4 kk = s_cxyz[bufc][cw];
    lastx = kk.x; lasty = kk.y; lastz = kk.z;
    if (tid == 0) s_k[k] = kk;
    bufc ^= 1;
  }
}

// ---------------------------------------------------------------- FPS: grid 12 = (class, batch, band), 1024 threads
__launch_bounds__(1024, 4)
__global__ void k_fps(const float* __restrict__ pts, const float* __restrict__ rngv,
                      float* __restrict__ out2) {
#pragma clang fp contract(off)
  const int blk = blockIdx.x;
  const int cls = blk / 6;                // 0: NL=4 (M<=4096), 1: NL=8 (M<=8192)
  const int sub = blk % 6;
  const int band = sub % 3, batch = sub / 3;
  const int K = (band == 0) ? 1024 : 512;
  const int off = (band == 0) ? 0 : (band == 1 ? 1024 : 1536);
  const int base = batch * NPTS_;

  __shared__ unsigned short s_idx[8192];    // 16 KB compacted -> original idx
  __shared__ float4 s_k[1024];              // 16 KB selected keypoints
  __shared__ u64 s_key[2][16];
  __shared__ float4 s_cxyz[2][16];
  __shared__ int s_wsum[16];

  const int tid = threadIdx.x, lane = tid & 63, wv = tid >> 6;

  // ---- mask own contiguous 16-point chunk (order-preserving compaction)
  unsigned int vm = 0u;
  for (int j = 0; j < 16; ++j) {
    float r = rngv[base + tid * 16 + j];
    bool sm = (r > 0.0f) && (r < 25.0f);
    bool lm = (r > 45.0f);
    bool v = (band == 0) ? sm : (band == 2 ? lm : (!lm && !sm));
    vm |= (v ? 1u : 0u) << j;
  }
  int cnt = __popc(vm);
  int inc = cnt;
  for (int d = 1; d < 64; d <<= 1) {
    int o = __shfl_up(inc, d);
    if (lane >= d) inc += o;
  }
  if (lane == 63) s_wsum[wv] = inc;
  __syncthreads();
  int woff = 0, M = 0;
  for (int w = 0; w < 16; ++w) {
    if (w < wv) woff += s_wsum[w];
    M += s_wsum[w];
  }
  // class check: exactly one class kernel-instance handles this band
  int myclass = (M <= 4096) ? 0 : 1;
  if (myclass != cls) return;

  int myoff = woff + inc - cnt;
  unsigned int t = vm;
  while (t) {
    int b = __builtin_ctz(t);
    t &= t - 1;
    if (myoff < 8192) s_idx[myoff] = (unsigned short)(tid * 16 + b);
    ++myoff;
  }
  __syncthreads();

  if (cls == 0) fps_core<4>(tid, lane, wv, M, K, base, pts, s_idx, s_k, s_key, s_cxyz);
  else          fps_core<8>(tid, lane, wv, M, K, base, pts, s_idx, s_k, s_key, s_cxyz);

  // ---- epilogue: stream keypoints to out2
  __syncthreads();
  const float batf = (float)batch;
  for (int i = tid; i < K; i += 1024) {
    int g = (batch * KTOT_ + off + i) * 4;
    float4 kk = s_k[i];
    out2[g + 0] = batf;
    out2[g + 1] = kk.x;
    out2[g + 2] = kk.y;
    out2[g + 3] = kk.z;
  }
}

// ---------------------------------------------------------------- bilinear BEV gather, native [B,C,H,W]
__launch_bounds__(256)
__global__ void k_bev(const float* __restrict__ sf, const float* __restrict__ out2,
                      float* __restrict__ out1) {
#pragma clang fp contract(off)
  int tid = threadIdx.x, lane = tid & 63, wv = tid >> 6;
  int g = blockIdx.x * 4 + wv;
  if (g >= ROWS_) return;
  int b = g >> 11;
  float xx = out2[g * 4 + 1], yy = out2[g * 4 + 2];
  float x = (xx - 0.0f) / 0.05f / 8.0f;
  float y = (yy - (-40.0f)) / 0.05f / 8.0f;
  int x0 = (int)floorf(x), y0 = (int)floorf(y);
  int x1 = x0 + 1, y1 = y0 + 1;
  x0 = min(max(x0, 0), IMW - 1); x1 = min(max(x1, 0), IMW - 1);
  y0 = min(max(y0, 0), IMH - 1); y1 = min(max(y1, 0), IMH - 1);
  float x0f = (float)x0, x1f = (float)x1, y0f = (float)y0, y1f = (float)y1;
  float wa = (x1f - x) * (y1f - y);
  float wb = (x1f - x) * (y - y0f);
  float wc = (x - x0f) * (y1f - y);
  float wd = (x - x0f) * (y - y0f);
  int oa = y0 * IMW + x0;
  int ob = y1 * IMW + x0;
  int oc = y0 * IMW + x1;
  int od = y1 * IMW + x1;
  const float* pb = sf + (size_t)b * IMC * IMH * IMW;
  for (int j = 0; j < 4; ++j) {
    int c = lane * 4 + j;
    const float* pc = pb + (size_t)c * (IMH * IMW);
    float o = pc[oa] * wa;
    o += pc[ob] * wb;
    o += pc[oc] * wc;
    o += pc[od] * wd;
    out1[(size_t)g * CIN_ + c] = o;
  }
}

// ---------------------------------------------------------------- SA: ball query + MLP + maxpool (wave per kp)
__launch_bounds__(256)
__global__ void k_sa(const float* __restrict__ pts, const float* __restrict__ out2,
                     const float* __restrict__ w0, const float* __restrict__ bn0,
                     const float* __restrict__ w1, const float* __restrict__ bn1,
                     float* __restrict__ out1) {
#pragma clang fp contract(off)
  __shared__ float s_w0[128];   // [2][4][16]
  __shared__ float s_w1[512];   // [2][16][16]
  __shared__ float s_s0[32], s_m0[32], s_b0[32];  // [2][16]
  __shared__ float s_s1[32], s_m1[32], s_b1[32];
  int tid = threadIdx.x;
  for (int i = tid; i < 128; i += 256) s_w0[i] = w0[i];
  for (int i = tid; i < 512; i += 256) s_w1[i] = w1[i];
  if (tid < 32) {
    int rad = tid >> 4, c = tid & 15;
    int bb = rad * 64;
    {
      float gg = bn0[bb + c], bbt = bn0[bb + 16 + c];
      float mm = bn0[bb + 32 + c], vv = bn0[bb + 48 + c];
      s_s0[tid] = gg / sqrtf(vv + 1e-5f); s_m0[tid] = mm; s_b0[tid] = bbt;
    }
    {
      float gg = bn1[bb + c], bbt = bn1[bb + 16 + c];
      float mm = bn1[bb + 32 + c], vv = bn1[bb + 48 + c];
      s_s1[tid] = gg / sqrtf(vv + 1e-5f); s_m1[tid] = mm; s_b1[tid] = bbt;
    }
  }
  __syncthreads();

  int lane = tid & 63, wv = tid >> 6;
  int g = blockIdx.x * 4 + wv;
  if (g >= ROWS_) return;
  int batch = g >> 11;
  int base = batch * NPTS_;
  float kx = out2[g * 4 + 1];
  float ky = out2[g * 4 + 2];
  float kz = out2[g * 4 + 3];

  int myrad = (lane >> 4) & 1, myslot = lane & 15;
  int c1 = 0, c2 = 0, first1 = -1, first2 = -1, myidx = -1;
  for (int r = 0; r < NPTS_ / 64; ++r) {
    int gi = (base + r * 64 + lane) * 5;
    float dx = kx - pts[gi + 1];
    float dy = ky - pts[gi + 2];
    float dz = kz - pts[gi + 3];
    float d = dx * dx;
    d += dy * dy;
    d += dz * dz;
    unsigned long long m1 = __ballot(d < 1.0f);
    unsigned long long m2 = __ballot(d < 4.0f);
    while (m1 && c1 < 16) {
      int bpos = __builtin_ctzll(m1); m1 &= m1 - 1;
      int pi = r * 64 + bpos;
      if (c1 == 0) first1 = pi;
      if (lane < 32 && myrad == 0 && c1 == myslot) myidx = pi;
      ++c1;
    }
    while (m2 && c2 < 16) {
      int bpos = __builtin_ctzll(m2); m2 &= m2 - 1;
      int pi = r * 64 + bpos;
      if (c2 == 0) first2 = pi;
      if (lane < 32 && myrad == 1 && c2 == myslot) myidx = pi;
      ++c2;
    }
    if (c1 >= 16 && c2 >= 16) break;
  }
  int fi = (myrad == 0) ? first1 : first2;
  bool use = (lane < 32) && (fi >= 0);
  if (myidx < 0) myidx = (fi >= 0) ? fi : 0;
  float gx = 0.f, gy = 0.f, gz = 0.f, gf = 0.f;
  if (use) {
    int gi = (base + myidx) * 5;
    gx = pts[gi + 1] - kx;
    gy = pts[gi + 2] - ky;
    gz = pts[gi + 3] - kz;
    gf = pts[gi + 4];
  }
  const float* W0 = s_w0 + myrad * 64;    // [4][16]
  const float* W1 = s_w1 + myrad * 256;   // [16][16]
  int bc = myrad * 16;
  float h1[16];
  for (int c = 0; c < 16; ++c) {
    float a = gx * W0[c];
    a += gy * W0[16 + c];
    a += gz * W0[32 + c];
    a += gf * W0[48 + c];
    h1[c] = fmaxf((a - s_m0[bc + c]) * s_s0[bc + c] + s_b0[bc + c], 0.f);
  }
  for (int c = 0; c < 16; ++c) {
    float a = 0.f;
    for (int k = 0; k < 16; ++k) a += h1[k] * W1[k * 16 + c];
    float h2 = fmaxf((a - s_m1[bc + c]) * s_s1[bc + c] + s_b1[bc + c], 0.f);
    h2 = fmaxf(h2, __shfl_xor(h2, 1));
    h2 = fmaxf(h2, __shfl_xor(h2, 2));
    h2 = fmaxf(h2, __shfl_xor(h2, 4));
    h2 = fmaxf(h2, __shfl_xor(h2, 8));
    if (lane < 32 && myslot == 0) {
      int col = 256 + myrad * 16 + c;
      out1[(size_t)g * CIN_ + col] = h2;
    }
  }
}

// ---------------------------------------------------------------- fusion: [4096,288]@[288,128] + BN + ReLU
__launch_bounds__(128)
__global__ void k_fuse(const float* __restrict__ out1, const float* __restrict__ fw,
                       const float* __restrict__ fbn, float* __restrict__ out0) {
  int r = blockIdx.x, c = threadIdx.x;
  __shared__ float sA[CIN_];
  for (int i = c; i < CIN_; i += 128) sA[i] = out1[(size_t)r * CIN_ + i];
  __syncthreads();
  float acc = 0.f;
  for (int k = 0; k < CIN_; ++k) acc += sA[k] * fw[k * COUT_ + c];
  float gg = fbn[c], bb = fbn[COUT_ + c];
  float mm = fbn[2 * COUT_ + c], vv = fbn[3 * COUT_ + c];
  float sc = gg / sqrtf(vv + 1e-5f);
  float o = fmaxf((acc - mm) * sc + bb, 0.f);
  out0[(size_t)r * COUT_ + c] = o;
}

// ---------------------------------------------------------------- launch (ZERO d_ws usage)
extern "C" void kernel_launch(void* const* d_in, const int* in_sizes, int n_in,
                              void* d_out, int out_size, void* d_ws, size_t ws_size,
                              hipStream_t stream) {
  const float* points = (const float*)d_in[0];
  const float* rng    = (const float*)d_in[1];
  const float* sf     = (const float*)d_in[2];
  const float* w0     = (const float*)d_in[3];
  const float* bn0    = (const float*)d_in[4];
  const float* w1     = (const float*)d_in[5];
  const float* bn1    = (const float*)d_in[6];
  const float* fw     = (const float*)d_in[7];
  const float* fbn    = (const float*)d_in[8];

  float* out0 = (float*)d_out;                         // fused [4096,128]
  float* out1 = out0 + (size_t)ROWS_ * COUT_;          // feats [4096,288]
  float* out2 = out1 + (size_t)ROWS_ * CIN_;           // point_coords [4096,4]

  k_fps<<<12, 1024, 0, stream>>>(points, rng, out2);
  k_bev<<<ROWS_ / 4, 256, 0, stream>>>(sf, out2, out1);
  k_sa<<<ROWS_ / 4, 256, 0, stream>>>(points, out2, w0, bn0, w1, bn1, out1);
  k_fuse<<<ROWS_, 128, 0, stream>>>(out1, fw, fbn, out0);
}

// Round 10
// 940.445 us; speedup vs baseline: 2.5492x; 1.3974x over previous
//
#include <hip/hip_runtime.h>
#include <hip/hip_bf16.h>
#include <climits>

#define NB 2
#define NPTS_ 16384
#define IMH 200
#define IMW 176
#define IMC 256
#define KTOT_ 2048
#define ROWS_ 4096
#define CIN_ 288
#define COUT_ 128

typedef unsigned long long u64;
typedef unsigned int u32;

// DPP wave64 reduction stages (VALU-only; result lands in lane 63).
#define DPP_MAXF(v, ctrl)                                                              \
  do {                                                                                 \
    int _s = __builtin_amdgcn_update_dpp(__float_as_int(v), __float_as_int(v), (ctrl), \
                                         0xF, 0xF, false);                             \
    (v) = fmaxf((v), __int_as_float(_s));                                              \
  } while (0)
#define DPP_MINU(v, ctrl)                                                              \
  do {                                                                                 \
    int _s = __builtin_amdgcn_update_dpp((int)(v), (int)(v), (ctrl), 0xF, 0xF, false); \
    (v) = ((u32)_s < (v)) ? (u32)_s : (v);                                             \
  } while (0)

// ---------------------------------------------------------------- FPS core
// NW waves (NW*64 threads), slot p = tid + j*NW*64. Scan tracks max-dist only;
// slot/coords recovered once per step by descending equality match (first-index
// tie-break). Wave reduce: DPP max-d + DPP min-p among ties (VALU only).
// Cross-wave: NW-key u64 tree in LDS. Key = (d_bits<<32)|~p: u64 max ==
// (max d, tie -> min compacted index).
template <int NW, int NL>
__device__ __forceinline__ void fps_core(
    int tid, int lane, int wv, int M, int K, int base,
    const float* __restrict__ pts,
    const unsigned short* __restrict__ s_idx,
    float4* __restrict__ s_k,
    u64 (* __restrict__ s_key)[16],
    float4 (* __restrict__ s_cxyz)[16]) {
#pragma clang fp contract(off)
  constexpr int STRIDE = NW * 64;
  float lx[NL], ly[NL], lz[NL], ld[NL];
#pragma unroll
  for (int j = 0; j < NL; ++j) {
    int p = tid + j * STRIDE;
    bool v = p < M;
    int oi = v ? (int)s_idx[p] : 0;
    int gi = (base + oi) * 5;
    lx[j] = pts[gi + 1];
    ly[j] = pts[gi + 2];
    lz[j] = pts[gi + 3];
    ld[j] = v ? 1e10f : -1.0f;   // invalid slots pinned at -1: never selected (bd >= 0 always)
  }
  int gi0 = (base + (int)s_idx[0]) * 5;
  float lastx = pts[gi0 + 1], lasty = pts[gi0 + 2], lastz = pts[gi0 + 3];
  if (tid == 0) s_k[0] = make_float4(lastx, lasty, lastz, 0.f);

  int bufc = 0;
  for (int k = 1; k < K; ++k) {
    // scan: update running min-dist; track only the max (slot 0 always valid since M > K >= 512... M > STRIDE holds for chosen NW)
    float bd = -1.0f;
#pragma unroll
    for (int j = 0; j < NL; ++j) {
      float dx = lx[j] - lastx;
      float dy = ly[j] - lasty;
      float dz = lz[j] - lastz;
      float d = dx * dx;
      d += dy * dy;
      d += dz * dz;
      float nd = fminf(ld[j], d);
      ld[j] = nd;
      bd = fmaxf(bd, nd);
    }
    // extract smallest slot j achieving bd (descending -> first index); bd>=0 never matches -1
    int bj = 0;
    float bx = lx[0], by = ly[0], bz = lz[0];
#pragma unroll
    for (int j = NL - 1; j >= 0; --j) {
      if (ld[j] == bd) { bj = j; bx = lx[j]; by = ly[j]; bz = lz[j]; }
    }
    int bp = tid + bj * STRIDE;

    // wave max-d via DPP (VALU only), broadcast from lane 63
    float rd = bd;
    DPP_MAXF(rd, 0x111);  // row_shr:1
    DPP_MAXF(rd, 0x112);  // row_shr:2
    DPP_MAXF(rd, 0x114);  // row_shr:4
    DPP_MAXF(rd, 0x118);  // row_shr:8
    DPP_MAXF(rd, 0x142);  // row_bcast:15
    DPP_MAXF(rd, 0x143);  // row_bcast:31
    float maxd = __int_as_float(__builtin_amdgcn_readlane(__float_as_int(rd), 63));

    // wave min-p among lanes holding maxd (p unique per lane -> unique winner)
    u32 pc = (bd == maxd) ? (u32)bp : 0xFFFFFFFFu;
    u32 rp = pc;
    DPP_MINU(rp, 0x111);
    DPP_MINU(rp, 0x112);
    DPP_MINU(rp, 0x114);
    DPP_MINU(rp, 0x118);
    DPP_MINU(rp, 0x142);
    DPP_MINU(rp, 0x143);
    u32 wp = (u32)__builtin_amdgcn_readlane((int)rp, 63);

    if (pc == wp) {   // the unique wave-winner lane still holds its local coords
      s_key[bufc][wv] = ((u64)__float_as_uint(maxd) << 32) | (u32)(~wp);
      s_cxyz[bufc][wv] = make_float4(bx, by, bz, 0.f);
    }
    __syncthreads();
    // cross-wave: reduce the NW wave keys (broadcast LDS b64 reads)
    u64 best = s_key[bufc][0];
#pragma unroll
    for (int w = 1; w < NW; ++w) {
      u64 cc = s_key[bufc][w];
      best = (cc > best) ? cc : best;
    }
    int cw = (int)((~(u32)best & (u32)(STRIDE - 1)) >> 6);   // winner tid -> wave
    float4 kk = s_cxyz[bufc][cw];
    lastx = kk.x; lasty = kk.y; lastz = kk.z;
    if (tid == 0) s_k[k] = kk;
    bufc ^= 1;
  }
}

// ---------------------------------------------------------------- FPS: 6 blocks = (batch, band), 1024 threads
// Compaction uses all 1024 threads; then only NW waves (band/M-dependent) stay
// for the serial loop (hardware barrier counts live waves only).
__launch_bounds__(1024, 4)
__global__ void k_fps(const float* __restrict__ pts, const float* __restrict__ rngv,
                      float* __restrict__ out2) {
#pragma clang fp contract(off)
  const int blk = blockIdx.x;
  const int band = blk % 3, batch = blk / 3;
  const int K = (band == 0) ? 1024 : 512;
  const int off = (band == 0) ? 0 : (band == 1 ? 1024 : 1536);
  const int base = batch * NPTS_;

  __shared__ unsigned short s_idx[NPTS_];   // 32 KB compacted -> original idx
  __shared__ float4 s_k[1024];              // 16 KB selected keypoints
  __shared__ u64 s_key[2][16];
  __shared__ float4 s_cxyz[2][16];
  __shared__ int s_wsum[16];

  const int tid = threadIdx.x, lane = tid & 63, wv = tid >> 6;

  // ---- mask own contiguous 16-point chunk (order-preserving compaction)
  unsigned int vm = 0u;
  for (int j = 0; j < 16; ++j) {
    float r = rngv[base + tid * 16 + j];
    bool sm = (r > 0.0f) && (r < 25.0f);
    bool lm = (r > 45.0f);
    bool v = (band == 0) ? sm : (band == 2 ? lm : (!lm && !sm));
    vm |= (v ? 1u : 0u) << j;
  }
  int cnt = __popc(vm);
  int inc = cnt;
  for (int d = 1; d < 64; d <<= 1) {
    int o = __shfl_up(inc, d);
    if (lane >= d) inc += o;
  }
  if (lane == 63) s_wsum[wv] = inc;
  __syncthreads();
  int woff = 0, M = 0;
  for (int w = 0; w < 16; ++w) {
    if (w < wv) woff += s_wsum[w];
    M += s_wsum[w];
  }
  int myoff = woff + inc - cnt;
  unsigned int t = vm;
  while (t) {
    int b = __builtin_ctz(t);
    t &= t - 1;
    s_idx[myoff++] = (unsigned short)(tid * 16 + b);
  }
  __syncthreads();

  // ---- band/M-dependent wave count + slot count (all register-resident)
  int sel;  // 0:(4,12) 1:(4,16) 2:(8,16) 3:(16,16)
  if (band == 0) {
    if (M <= 3072) sel = 0;
    else if (M <= 4096) sel = 1;
    else if (M <= 8192) sel = 2;
    else sel = 3;
  } else {
    sel = (M <= 8192) ? 2 : 3;
  }
  const int nw = (sel <= 1) ? 4 : (sel == 2 ? 8 : 16);
  if (tid >= nw * 64) return;   // surplus waves exit; barriers track live waves

  if (sel == 0)      fps_core<4, 12>(tid, lane, wv, M, K, base, pts, s_idx, s_k, s_key, s_cxyz);
  else if (sel == 1) fps_core<4, 16>(tid, lane, wv, M, K, base, pts, s_idx, s_k, s_key, s_cxyz);
  else if (sel == 2) fps_core<8, 16>(tid, lane, wv, M, K, base, pts, s_idx, s_k, s_key, s_cxyz);
  else               fps_core<16, 16>(tid, lane, wv, M, K, base, pts, s_idx, s_k, s_key, s_cxyz);

  // ---- epilogue: stream keypoints to out2
  __syncthreads();
  const float batf = (float)batch;
  for (int i = tid; i < K; i += nw * 64) {
    int g = (batch * KTOT_ + off + i) * 4;
    float4 kk = s_k[i];
    out2[g + 0] = batf;
    out2[g + 1] = kk.x;
    out2[g + 2] = kk.y;
    out2[g + 3] = kk.z;
  }
}

// ---------------------------------------------------------------- bilinear BEV gather, native [B,C,H,W]
__launch_bounds__(256)
__global__ void k_bev(const float* __restrict__ sf, const float* __restrict__ out2,
                      float* __restrict__ out1) {
#pragma clang fp contract(off)
  int tid = threadIdx.x, lane = tid & 63, wv = tid >> 6;
  int g = blockIdx.x * 4 + wv;
  if (g >= ROWS_) return;
  int b = g >> 11;
  float xx = out2[g * 4 + 1], yy = out2[g * 4 + 2];
  float x = (xx - 0.0f) / 0.05f / 8.0f;
  float y = (yy - (-40.0f)) / 0.05f / 8.0f;
  int x0 = (int)floorf(x), y0 = (int)floorf(y);
  int x1 = x0 + 1, y1 = y0 + 1;
  x0 = min(max(x0, 0), IMW - 1); x1 = min(max(x1, 0), IMW - 1);
  y0 = min(max(y0, 0), IMH - 1); y1 = min(max(y1, 0), IMH - 1);
  float x0f = (float)x0, x1f = (float)x1, y0f = (float)y0, y1f = (float)y1;
  float wa = (x1f - x) * (y1f - y);
  float wb = (x1f - x) * (y - y0f);
  float wc = (x - x0f) * (y1f - y);
  float wd = (x - x0f) * (y - y0f);
  int oa = y0 * IMW + x0;
  int ob = y1 * IMW + x0;
  int oc = y0 * IMW + x1;
  int od = y1 * IMW + x1;
  const float* pb = sf + (size_t)b * IMC * IMH * IMW;
  for (int j = 0; j < 4; ++j) {
    int c = lane * 4 + j;
    const float* pc = pb + (size_t)c * (IMH * IMW);
    float o = pc[oa] * wa;
    o += pc[ob] * wb;
    o += pc[oc] * wc;
    o += pc[od] * wd;
    out1[(size_t)g * CIN_ + c] = o;
  }
}

// ---------------------------------------------------------------- SA: ball query + MLP + maxpool (wave per kp)
__launch_bounds__(256)
__global__ void k_sa(const float* __restrict__ pts, const float* __restrict__ out2,
                     const float* __restrict__ w0, const float* __restrict__ bn0,
                     const float* __restrict__ w1, const float* __restrict__ bn1,
                     float* __restrict__ out1) {
#pragma clang fp contract(off)
  __shared__ float s_w0[128];   // [2][4][16]
  __shared__ float s_w1[512];   // [2][16][16]
  __shared__ float s_s0[32], s_m0[32], s_b0[32];  // [2][16]
  __shared__ float s_s1[32], s_m1[32], s_b1[32];
  int tid = threadIdx.x;
  for (int i = tid; i < 128; i += 256) s_w0[i] = w0[i];
  for (int i = tid; i < 512; i += 256) s_w1[i] = w1[i];
  if (tid < 32) {
    int rad = tid >> 4, c = tid & 15;
    int bb = rad * 64;
    {
      float gg = bn0[bb + c], bbt = bn0[bb + 16 + c];
      float mm = bn0[bb + 32 + c], vv = bn0[bb + 48 + c];
      s_s0[tid] = gg / sqrtf(vv + 1e-5f); s_m0[tid] = mm; s_b0[tid] = bbt;
    }
    {
      float gg = bn1[bb + c], bbt = bn1[bb + 16 + c];
      float mm = bn1[bb + 32 + c], vv = bn1[bb + 48 + c];
      s_s1[tid] = gg / sqrtf(vv + 1e-5f); s_m1[tid] = mm; s_b1[tid] = bbt;
    }
  }
  __syncthreads();

  int lane = tid & 63, wv = tid >> 6;
  int g = blockIdx.x * 4 + wv;
  if (g >= ROWS_) return;
  int batch = g >> 11;
  int base = batch * NPTS_;
  float kx = out2[g * 4 + 1];
  float ky = out2[g * 4 + 2];
  float kz = out2[g * 4 + 3];

  int myrad = (lane >> 4) & 1, myslot = lane & 15;
  int c1 = 0, c2 = 0, first1 = -1, first2 = -1, myidx = -1;
  for (int r = 0; r < NPTS_ / 64; ++r) {
    int gi = (base + r * 64 + lane) * 5;
    float dx = kx - pts[gi + 1];
    float dy = ky - pts[gi + 2];
    float dz = kz - pts[gi + 3];
    float d = dx * dx;
    d += dy * dy;
    d += dz * dz;
    unsigned long long m1 = __ballot(d < 1.0f);
    unsigned long long m2 = __ballot(d < 4.0f);
    while (m1 && c1 < 16) {
      int bpos = __builtin_ctzll(m1); m1 &= m1 - 1;
      int pi = r * 64 + bpos;
      if (c1 == 0) first1 = pi;
      if (lane < 32 && myrad == 0 && c1 == myslot) myidx = pi;
      ++c1;
    }
    while (m2 && c2 < 16) {
      int bpos = __builtin_ctzll(m2); m2 &= m2 - 1;
      int pi = r * 64 + bpos;
      if (c2 == 0) first2 = pi;
      if (lane < 32 && myrad == 1 && c2 == myslot) myidx = pi;
      ++c2;
    }
    if (c1 >= 16 && c2 >= 16) break;
  }
  int fi = (myrad == 0) ? first1 : first2;
  bool use = (lane < 32) && (fi >= 0);
  if (myidx < 0) myidx = (fi >= 0) ? fi : 0;
  float gx = 0.f, gy = 0.f, gz = 0.f, gf = 0.f;
  if (use) {
    int gi = (base + myidx) * 5;
    gx = pts[gi + 1] - kx;
    gy = pts[gi + 2] - ky;
    gz = pts[gi + 3] - kz;
    gf = pts[gi + 4];
  }
  const float* W0 = s_w0 + myrad * 64;    // [4][16]
  const float* W1 = s_w1 + myrad * 256;   // [16][16]
  int bc = myrad * 16;
  float h1[16];
  for (int c = 0; c < 16; ++c) {
    float a = gx * W0[c];
    a += gy * W0[16 + c];
    a += gz * W0[32 + c];
    a += gf * W0[48 + c];
    h1[c] = fmaxf((a - s_m0[bc + c]) * s_s0[bc + c] + s_b0[bc + c], 0.f);
  }
  for (int c = 0; c < 16; ++c) {
    float a = 0.f;
    for (int k = 0; k < 16; ++k) a += h1[k] * W1[k * 16 + c];
    float h2 = fmaxf((a - s_m1[bc + c]) * s_s1[bc + c] + s_b1[bc + c], 0.f);
    h2 = fmaxf(h2, __shfl_xor(h2, 1));
    h2 = fmaxf(h2, __shfl_xor(h2, 2));
    h2 = fmaxf(h2, __shfl_xor(h2, 4));
    h2 = fmaxf(h2, __shfl_xor(h2, 8));
    if (lane < 32 && myslot == 0) {
      int col = 256 + myrad * 16 + c;
      out1[(size_t)g * CIN_ + col] = h2;
    }
  }
}

// ---------------------------------------------------------------- fusion: [4096,288]@[288,128] + BN + ReLU
__launch_bounds__(128)
__global__ void k_fuse(const float* __restrict__ out1, const float* __restrict__ fw,
                       const float* __restrict__ fbn, float* __restrict__ out0) {
  int r = blockIdx.x, c = threadIdx.x;
  __shared__ float sA[CIN_];
  for (int i = c; i < CIN_; i += 128) sA[i] = out1[(size_t)r * CIN_ + i];
  __syncthreads();
  float acc = 0.f;
  for (int k = 0; k < CIN_; ++k) acc += sA[k] * fw[k * COUT_ + c];
  float gg = fbn[c], bb = fbn[COUT_ + c];
  float mm = fbn[2 * COUT_ + c], vv = fbn[3 * COUT_ + c];
  float sc = gg / sqrtf(vv + 1e-5f);
  float o = fmaxf((acc - mm) * sc + bb, 0.f);
  out0[(size_t)r * COUT_ + c] = o;
}

// ---------------------------------------------------------------- launch (ZERO d_ws usage)
extern "C" void kernel_launch(void* const* d_in, const int* in_sizes, int n_in,
                              void* d_out, int out_size, void* d_ws, size_t ws_size,
                              hipStream_t stream) {
  const float* points = (const float*)d_in[0];
  const float* rng    = (const float*)d_in[1];
  const float* sf     = (const float*)d_in[2];
  const float* w0     = (const float*)d_in[3];
  const float* bn0    = (const float*)d_in[4];
  const float* w1     = (const float*)d_in[5];
  const float* bn1    = (const float*)d_in[6];
  const float* fw     = (const float*)d_in[7];
  const float* fbn    = (const float*)d_in[8];

  float* out0 = (float*)d_out;                         // fused [4096,128]
  float* out1 = out0 + (size_t)ROWS_ * COUT_;          // feats [4096,288]
  float* out2 = out1 + (size_t)ROWS_ * CIN_;           // point_coords [4096,4]

  k_fps<<<6, 1024, 0, stream>>>(points, rng, out2);
  k_bev<<<ROWS_ / 4, 256, 0, stream>>>(sf, out2, out1);
  k_sa<<<ROWS_ / 4, 256, 0, stream>>>(points, out2, w0, bn0, w1, bn1, out1);
  k_fuse<<<ROWS_, 128, 0, stream>>>(out1, fw, fbn, out0);
}